// Round 1
// baseline (17912.482 us; speedup 1.0000x reference)
//
#include <hip/hip_runtime.h>
#include <hip/hip_bf16.h>

#define NN 100000
#define NE 3200000
#define DH 128
#define NL 3
#define NG 64
#define BN_EPS 1e-5f

__device__ __forceinline__ void atomAdd(float* p, float v) {
    __hip_atomic_fetch_add(p, v, __ATOMIC_RELAXED, __HIP_MEMORY_SCOPE_AGENT);
}

__global__ void k_init_deg(float* __restrict__ deg) {
    int i = blockIdx.x * 256 + threadIdx.x;
    if (i < NN) deg[i] = 1.0f;  // self-loop
}

__global__ void k_count_deg(const int* __restrict__ dst, float* __restrict__ deg) {
    int e = blockIdx.x * 256 + threadIdx.x;
    if (e < NE) atomAdd(&deg[dst[e]], 1.0f);
}

__global__ void k_dinv(float* __restrict__ deg) {
    int i = blockIdx.x * 256 + threadIdx.x;
    if (i < NN) deg[i] = rsqrtf(deg[i]);  // deg >= 1 always
}

__global__ void k_starts(const int* __restrict__ batch, int* __restrict__ starts) {
    int i = blockIdx.x * 256 + threadIdx.x;
    if (i >= NN) return;
    int g  = batch[i];
    int gp = (i == 0) ? -1 : batch[i - 1];
    for (int gg = gp + 1; gg <= g; ++gg) starts[gg] = i;
    if (i == NN - 1) {
        for (int gg = g + 1; gg <= NG; ++gg) starts[gg] = NN;
    }
}

// S[i] = dinv[i]^2 * X[i]  (self-loop term); also zeroes BN stats accumulator
__global__ void k_self_init(const float* __restrict__ X, const float* __restrict__ dinv,
                            float* __restrict__ S, float* __restrict__ stats) {
    int i = blockIdx.x * 256 + threadIdx.x;
    if (blockIdx.x == 0 && threadIdx.x < 256) stats[threadIdx.x] = 0.0f;
    if (i < NN * 32) {
        int r = i >> 5;
        int c = (i & 31) << 2;
        float w = dinv[r]; w *= w;
        float4 v = *(const float4*)&X[(size_t)r * DH + c];
        float4 m; m.x = w * v.x; m.y = w * v.y; m.z = w * v.z; m.w = w * v.w;
        *(float4*)&S[(size_t)r * DH + c] = m;
    }
}

// one edge handled by 32 consecutive threads (float4 each): S[dst] += norm * X[src]
__global__ void k_scatter(const float* __restrict__ X, float* __restrict__ S,
                          const int* __restrict__ src, const int* __restrict__ dst,
                          const float* __restrict__ dinv) {
    long i = (long)blockIdx.x * 256 + threadIdx.x;   // grid is exact: NE*32 threads
    int e = (int)(i >> 5);
    int c = (int)(i & 31) << 2;
    int s = src[e], d = dst[e];
    float w = dinv[s] * dinv[d];
    float4 v = *(const float4*)&X[(size_t)s * DH + c];
    float* out = &S[(size_t)d * DH + c];
    atomAdd(out + 0, w * v.x);
    atomAdd(out + 1, w * v.y);
    atomAdd(out + 2, w * v.z);
    atomAdd(out + 3, w * v.w);
}

// Y = X @ W (W staged in LDS, 64KB), BN stats (col sum / sumsq) fused into epilogue
__global__ __launch_bounds__(256) void k_gemm_stats(const float* __restrict__ X,
                                                    const float* __restrict__ W,
                                                    float* __restrict__ Y,
                                                    float* __restrict__ stats) {
    __shared__ float wlds[DH * DH];
    int t = threadIdx.x;
    for (int i = t * 4; i < DH * DH; i += 1024)
        *(float4*)&wlds[i] = *(const float4*)&W[i];
    __syncthreads();
    int cg = t & 31, rr = t >> 5;
    int row0 = blockIdx.x * 256;
    float ps0 = 0, ps1 = 0, ps2 = 0, ps3 = 0;
    float q0 = 0, q1 = 0, q2 = 0, q3 = 0;
    for (int it = 0; it < 32; ++it) {
        int r = row0 + it * 8 + rr;
        if (r >= NN) break;  // r monotone in it; no sync inside loop
        const float* xr = X + (size_t)r * DH;
        float a0 = 0, a1 = 0, a2 = 0, a3 = 0;
#pragma unroll 8
        for (int k = 0; k < DH; ++k) {
            float xk = xr[k];  // broadcast across the 32 lanes sharing this row
            const float4 w4 = *(const float4*)&wlds[(k << 7) + (cg << 2)];
            a0 = fmaf(xk, w4.x, a0);
            a1 = fmaf(xk, w4.y, a1);
            a2 = fmaf(xk, w4.z, a2);
            a3 = fmaf(xk, w4.w, a3);
        }
        float4 o; o.x = a0; o.y = a1; o.z = a2; o.w = a3;
        *(float4*)&Y[(size_t)r * DH + (cg << 2)] = o;
        ps0 += a0; ps1 += a1; ps2 += a2; ps3 += a3;
        q0 = fmaf(a0, a0, q0); q1 = fmaf(a1, a1, q1);
        q2 = fmaf(a2, a2, q2); q3 = fmaf(a3, a3, q3);
    }
    int c = cg << 2;
    atomAdd(&stats[c + 0], ps0); atomAdd(&stats[c + 1], ps1);
    atomAdd(&stats[c + 2], ps2); atomAdd(&stats[c + 3], ps3);
    atomAdd(&stats[DH + c + 0], q0); atomAdd(&stats[DH + c + 1], q1);
    atomAdd(&stats[DH + c + 2], q2); atomAdd(&stats[DH + c + 3], q3);
}

__global__ void k_bn_relu(float* __restrict__ H, const float* __restrict__ stats,
                          const float* __restrict__ gamma, const float* __restrict__ beta) {
    int i = blockIdx.x * 256 + threadIdx.x;
    if (i >= NN * 32) return;
    int r = i >> 5;
    int c = (i & 31) << 2;
    float4 v = *(float4*)&H[(size_t)r * DH + c];
    const float inv_n = 1.0f / NN;
    float vv[4] = {v.x, v.y, v.z, v.w};
    float out[4];
#pragma unroll
    for (int j = 0; j < 4; ++j) {
        float mean = stats[c + j] * inv_n;
        float var  = stats[DH + c + j] * inv_n - mean * mean;
        float sc   = gamma[c + j] * rsqrtf(var + BN_EPS);
        float y    = (vv[j] - mean) * sc + beta[c + j];
        out[j] = fmaxf(y, 0.0f);
    }
    float4 o = {out[0], out[1], out[2], out[3]};
    *(float4*)&H[(size_t)r * DH + c] = o;
}

// one block per graph (batch is sorted): mean over contiguous row range
__global__ void k_pool(const float* __restrict__ H, const int* __restrict__ starts,
                       float* __restrict__ pooled) {
    int g = blockIdx.x;
    int f = threadIdx.x;  // 128 threads
    int s = starts[g], e = starts[g + 1];
    float acc = 0.0f;
    for (int r = s; r < e; ++r) acc += H[(size_t)r * DH + f];
    float cnt = (float)(e - s);
    pooled[(g << 7) + f] = acc / fmaxf(cnt, 1.0f);
}

// out = relu(pooled @ w1 + b1) @ w2 + b2 ; single block
__global__ void k_mlp(const float* __restrict__ pooled, const float* __restrict__ w1,
                      const float* __restrict__ b1, const float* __restrict__ w2,
                      const float* __restrict__ b2, float* __restrict__ out) {
    __shared__ float hid[NG * DH];  // 32 KB
    int t = threadIdx.x;            // 256
    for (int idx = t; idx < NG * DH; idx += 256) {
        int g = idx >> 7, j = idx & 127;
        float s = b1[j];
        for (int k = 0; k < DH; ++k)
            s = fmaf(pooled[(g << 7) + k], w1[(k << 7) + j], s);
        hid[idx] = fmaxf(s, 0.0f);
    }
    __syncthreads();
    if (t < NG) {
        float s = b2[0];
        for (int j = 0; j < DH; ++j)
            s = fmaf(hid[(t << 7) + j], w2[j], s);
        out[t] = s;
    }
}

extern "C" void kernel_launch(void* const* d_in, const int* in_sizes, int n_in,
                              void* d_out, int out_size, void* d_ws, size_t ws_size,
                              hipStream_t stream) {
    const float* x      = (const float*)d_in[0];
    const int*   ei     = (const int*)d_in[1];
    const int*   batch  = (const int*)d_in[2];
    const float* conv_w = (const float*)d_in[3];
    // d_in[4] = conv_b: cancels exactly inside BatchNorm -> unused
    const float* bn_g   = (const float*)d_in[5];
    const float* bn_b   = (const float*)d_in[6];
    const float* w1     = (const float*)d_in[7];
    const float* b1     = (const float*)d_in[8];
    const float* w2     = (const float*)d_in[9];
    const float* b2     = (const float*)d_in[10];
    const int* src = ei;
    const int* dst = ei + NE;

    float* bufA   = (float*)d_ws;                  // N*D  (layer output / next input)
    float* bufB   = bufA + (size_t)NN * DH;        // N*D  (aggregation buffer)
    float* dinv   = bufB + (size_t)NN * DH;        // N    (deg -> dinv in place)
    float* stats  = dinv + NN;                     // 256  (colsum | colsumsq)
    float* pooled = stats + 256;                   // 64*128
    int*   starts = (int*)(pooled + NG * DH);      // 65

    k_init_deg <<<(NN + 255) / 256, 256, 0, stream>>>(dinv);
    k_count_deg<<<(NE + 255) / 256, 256, 0, stream>>>(dst, dinv);
    k_dinv     <<<(NN + 255) / 256, 256, 0, stream>>>(dinv);
    k_starts   <<<(NN + 255) / 256, 256, 0, stream>>>(batch, starts);

    const float* X = x;
    for (int l = 0; l < NL; ++l) {
        k_self_init<<<12500, 256, 0, stream>>>(X, dinv, bufB, stats);
        k_scatter  <<<400000, 256, 0, stream>>>(X, bufB, src, dst, dinv);
        k_gemm_stats<<<(NN + 255) / 256, 256, 0, stream>>>(
            bufB, conv_w + (size_t)l * DH * DH, bufA, stats);
        k_bn_relu  <<<12500, 256, 0, stream>>>(bufA, stats, bn_g + l * DH, bn_b + l * DH);
        X = bufA;
    }
    k_pool<<<NG, DH, 0, stream>>>(bufA, starts, pooled);
    k_mlp <<<1, 256, 0, stream>>>(pooled, w1, b1, w2, b2, (float*)d_out);
}

// Round 2
// 2750.398 us; speedup vs baseline: 6.5127x; 6.5127x over previous
//
#include <hip/hip_runtime.h>
#include <hip/hip_bf16.h>

#define NN 100000
#define NE 3200000
#define DH 128
#define NL 3
#define NG 64
#define BN_EPS 1e-5f

__device__ __forceinline__ void atomAddF(float* p, float v) {
    __hip_atomic_fetch_add(p, v, __ATOMIC_RELAXED, __HIP_MEMORY_SCOPE_AGENT);
}
__device__ __forceinline__ int atomAddI(int* p, int v) {
    return __hip_atomic_fetch_add(p, v, __ATOMIC_RELAXED, __HIP_MEMORY_SCOPE_AGENT);
}

__global__ void k_zero(int* __restrict__ cnt, int* __restrict__ gcounter) {
    int i = blockIdx.x * 256 + threadIdx.x;
    if (i < NN) cnt[i] = 0;
    if (i == 0) *gcounter = 0;
}

__global__ void k_count(const int* __restrict__ dst, int* __restrict__ cnt) {
    int e = blockIdx.x * 256 + threadIdx.x;
    if (e < NE) atomAddI(&cnt[dst[e]], 1);
}

// off[i] = contiguous range start (order arbitrary); cursor[i] = off[i];
// dinv[i] = rsqrt(in_deg + 1 self-loop)
__global__ void k_offsets(const int* __restrict__ cnt, int* __restrict__ off,
                          int* __restrict__ cursor, float* __restrict__ dinv,
                          int* __restrict__ gcounter) {
    int i = blockIdx.x * 256 + threadIdx.x;
    if (i >= NN) return;
    int c = cnt[i];
    int o = atomAddI(gcounter, c);
    off[i] = o;
    cursor[i] = o;
    dinv[i] = rsqrtf((float)c + 1.0f);
}

// edata[pos] = (src, dinv[src])  -- packed so the hot loop has ONE uniform 8B load per edge
__global__ void k_permute(const int* __restrict__ src, const int* __restrict__ dst,
                          const float* __restrict__ dinv, int* __restrict__ cursor,
                          int2* __restrict__ edata) {
    int e = blockIdx.x * 256 + threadIdx.x;
    if (e >= NE) return;
    int s = src[e], d = dst[e];
    int pos = atomAddI(&cursor[d], 1);
    edata[pos] = make_int2(s, __float_as_int(dinv[s]));
}

__global__ void k_starts(const int* __restrict__ batch, int* __restrict__ starts) {
    int i = blockIdx.x * 256 + threadIdx.x;
    if (i >= NN) return;
    int g  = batch[i];
    int gp = (i == 0) ? -1 : batch[i - 1];
    for (int gg = gp + 1; gg <= g; ++gg) starts[gg] = i;
    if (i == NN - 1) {
        for (int gg = g + 1; gg <= NG; ++gg) starts[gg] = NN;
    }
}

// One wave per dst node. S[d] = dinv[d] * sum_e dinv[s]*X[s]  +  dinv[d]^2 * X[d]
// No atomics: register accumulate, one coalesced write. Also zeroes BN stats.
__global__ __launch_bounds__(256) void k_aggregate(const float* __restrict__ X,
        const int2* __restrict__ ed, const int* __restrict__ off,
        const int* __restrict__ cnt, const float* __restrict__ dinv,
        float* __restrict__ S, float* __restrict__ stats) {
    if (blockIdx.x == 0 && threadIdx.x < 256) stats[threadIdx.x] = 0.0f;
    int w = (blockIdx.x << 2) + (threadIdx.x >> 6);  // 4 waves/block
    if (w >= NN) return;
    int lane = threadIdx.x & 63;
    int o = __builtin_amdgcn_readfirstlane(off[w]);
    int n = __builtin_amdgcn_readfirstlane(cnt[w]);
    const int2* e = ed + o;
    int col = lane << 1;
    float ax = 0.0f, ay = 0.0f;
    int j = 0;
    for (; j + 4 <= n; j += 4) {
        int2 e0 = e[j], e1 = e[j + 1], e2 = e[j + 2], e3 = e[j + 3];
        float2 v0 = *(const float2*)&X[(size_t)e0.x * DH + col];
        float2 v1 = *(const float2*)&X[(size_t)e1.x * DH + col];
        float2 v2 = *(const float2*)&X[(size_t)e2.x * DH + col];
        float2 v3 = *(const float2*)&X[(size_t)e3.x * DH + col];
        float w0 = __int_as_float(e0.y), w1 = __int_as_float(e1.y);
        float w2 = __int_as_float(e2.y), w3 = __int_as_float(e3.y);
        ax = fmaf(w0, v0.x, ax); ay = fmaf(w0, v0.y, ay);
        ax = fmaf(w1, v1.x, ax); ay = fmaf(w1, v1.y, ay);
        ax = fmaf(w2, v2.x, ax); ay = fmaf(w2, v2.y, ay);
        ax = fmaf(w3, v3.x, ax); ay = fmaf(w3, v3.y, ay);
    }
    for (; j < n; ++j) {
        int2 e0 = e[j];
        float2 v0 = *(const float2*)&X[(size_t)e0.x * DH + col];
        float w0 = __int_as_float(e0.y);
        ax = fmaf(w0, v0.x, ax); ay = fmaf(w0, v0.y, ay);
    }
    float di = dinv[w];
    float2 sv = *(const float2*)&X[(size_t)w * DH + col];
    float2 out;
    out.x = fmaf(di, ax, di * di * sv.x);
    out.y = fmaf(di, ay, di * di * sv.y);
    *(float2*)&S[(size_t)w * DH + col] = out;
}

// Y = X @ W (W staged in LDS), BN stats (col sum / sumsq) fused into epilogue
__global__ __launch_bounds__(256) void k_gemm_stats(const float* __restrict__ X,
                                                    const float* __restrict__ W,
                                                    float* __restrict__ Y,
                                                    float* __restrict__ stats) {
    __shared__ float wlds[DH * DH];
    int t = threadIdx.x;
    for (int i = t * 4; i < DH * DH; i += 1024)
        *(float4*)&wlds[i] = *(const float4*)&W[i];
    __syncthreads();
    int cg = t & 31, rr = t >> 5;
    int row0 = blockIdx.x * 256;
    float ps0 = 0, ps1 = 0, ps2 = 0, ps3 = 0;
    float q0 = 0, q1 = 0, q2 = 0, q3 = 0;
    for (int it = 0; it < 32; ++it) {
        int r = row0 + it * 8 + rr;
        if (r >= NN) break;
        const float* xr = X + (size_t)r * DH;
        float a0 = 0, a1 = 0, a2 = 0, a3 = 0;
#pragma unroll 8
        for (int k = 0; k < DH; ++k) {
            float xk = xr[k];
            const float4 w4 = *(const float4*)&wlds[(k << 7) + (cg << 2)];
            a0 = fmaf(xk, w4.x, a0);
            a1 = fmaf(xk, w4.y, a1);
            a2 = fmaf(xk, w4.z, a2);
            a3 = fmaf(xk, w4.w, a3);
        }
        float4 o; o.x = a0; o.y = a1; o.z = a2; o.w = a3;
        *(float4*)&Y[(size_t)r * DH + (cg << 2)] = o;
        ps0 += a0; ps1 += a1; ps2 += a2; ps3 += a3;
        q0 = fmaf(a0, a0, q0); q1 = fmaf(a1, a1, q1);
        q2 = fmaf(a2, a2, q2); q3 = fmaf(a3, a3, q3);
    }
    int c = cg << 2;
    atomAddF(&stats[c + 0], ps0); atomAddF(&stats[c + 1], ps1);
    atomAddF(&stats[c + 2], ps2); atomAddF(&stats[c + 3], ps3);
    atomAddF(&stats[DH + c + 0], q0); atomAddF(&stats[DH + c + 1], q1);
    atomAddF(&stats[DH + c + 2], q2); atomAddF(&stats[DH + c + 3], q3);
}

__global__ void k_bn_relu(float* __restrict__ H, const float* __restrict__ stats,
                          const float* __restrict__ gamma, const float* __restrict__ beta) {
    int i = blockIdx.x * 256 + threadIdx.x;
    if (i >= NN * 32) return;
    int r = i >> 5;
    int c = (i & 31) << 2;
    float4 v = *(float4*)&H[(size_t)r * DH + c];
    const float inv_n = 1.0f / NN;
    float vv[4] = {v.x, v.y, v.z, v.w};
    float out[4];
#pragma unroll
    for (int j = 0; j < 4; ++j) {
        float mean = stats[c + j] * inv_n;
        float var  = stats[DH + c + j] * inv_n - mean * mean;
        float sc   = gamma[c + j] * rsqrtf(var + BN_EPS);
        float y    = (vv[j] - mean) * sc + beta[c + j];
        out[j] = fmaxf(y, 0.0f);
    }
    float4 o = {out[0], out[1], out[2], out[3]};
    *(float4*)&H[(size_t)r * DH + c] = o;
}

__global__ void k_pool(const float* __restrict__ H, const int* __restrict__ starts,
                       float* __restrict__ pooled) {
    int g = blockIdx.x;
    int f = threadIdx.x;  // 128 threads
    int s = starts[g], e = starts[g + 1];
    float acc = 0.0f;
    for (int r = s; r < e; ++r) acc += H[(size_t)r * DH + f];
    float cnt = (float)(e - s);
    pooled[(g << 7) + f] = acc / fmaxf(cnt, 1.0f);
}

__global__ void k_mlp(const float* __restrict__ pooled, const float* __restrict__ w1,
                      const float* __restrict__ b1, const float* __restrict__ w2,
                      const float* __restrict__ b2, float* __restrict__ out) {
    __shared__ float hid[NG * DH];
    int t = threadIdx.x;  // 256
    for (int idx = t; idx < NG * DH; idx += 256) {
        int g = idx >> 7, j = idx & 127;
        float s = b1[j];
        for (int k = 0; k < DH; ++k)
            s = fmaf(pooled[(g << 7) + k], w1[(k << 7) + j], s);
        hid[idx] = fmaxf(s, 0.0f);
    }
    __syncthreads();
    if (t < NG) {
        float s = b2[0];
        for (int j = 0; j < DH; ++j)
            s = fmaf(hid[(t << 7) + j], w2[j], s);
        out[t] = s;
    }
}

extern "C" void kernel_launch(void* const* d_in, const int* in_sizes, int n_in,
                              void* d_out, int out_size, void* d_ws, size_t ws_size,
                              hipStream_t stream) {
    const float* x      = (const float*)d_in[0];
    const int*   ei     = (const int*)d_in[1];
    const int*   batch  = (const int*)d_in[2];
    const float* conv_w = (const float*)d_in[3];
    // d_in[4] = conv_b: cancels exactly inside BatchNorm -> unused
    const float* bn_g   = (const float*)d_in[5];
    const float* bn_b   = (const float*)d_in[6];
    const float* w1     = (const float*)d_in[7];
    const float* b1     = (const float*)d_in[8];
    const float* w2     = (const float*)d_in[9];
    const float* b2     = (const float*)d_in[10];
    const int* src = ei;
    const int* dst = ei + NE;

    float* bufA     = (float*)d_ws;                 // NN*DH
    float* bufB     = bufA + (size_t)NN * DH;       // NN*DH
    float* dinv     = bufB + (size_t)NN * DH;       // NN
    float* stats    = dinv + NN;                    // 256
    float* pooled   = stats + 256;                  // NG*DH
    int*   starts   = (int*)(pooled + NG * DH);     // 72 (NG+1, padded)
    int*   cnt      = starts + 72;                  // NN
    int*   off      = cnt + NN;                     // NN
    int*   cursor   = off + NN;                     // NN
    int*   gcounter = cursor + NN;                  // 8 (padded, keeps 8B align)
    int2*  edata    = (int2*)(gcounter + 8);        // NE int2 = 25.6 MB

    // ---- one-time CSR build (order within a node's range is nondeterministic,
    //      but the per-node edge SET is fixed; f32 sum reorder << threshold) ----
    k_zero   <<<(NN + 255) / 256, 256, 0, stream>>>(cnt, gcounter);
    k_count  <<<(NE + 255) / 256, 256, 0, stream>>>(dst, cnt);
    k_offsets<<<(NN + 255) / 256, 256, 0, stream>>>(cnt, off, cursor, dinv, gcounter);
    k_permute<<<(NE + 255) / 256, 256, 0, stream>>>(src, dst, dinv, cursor, edata);
    k_starts <<<(NN + 255) / 256, 256, 0, stream>>>(batch, starts);

    const float* X = x;
    for (int l = 0; l < NL; ++l) {
        k_aggregate <<<25000, 256, 0, stream>>>(X, edata, off, cnt, dinv, bufB, stats);
        k_gemm_stats<<<(NN + 255) / 256, 256, 0, stream>>>(
            bufB, conv_w + (size_t)l * DH * DH, bufA, stats);
        k_bn_relu   <<<12500, 256, 0, stream>>>(bufA, stats, bn_g + l * DH, bn_b + l * DH);
        X = bufA;
    }
    k_pool<<<NG, DH, 0, stream>>>(bufA, starts, pooled);
    k_mlp <<<1, 256, 0, stream>>>(pooled, w1, b1, w2, b2, (float*)d_out);
}

// Round 3
// 2254.598 us; speedup vs baseline: 7.9449x; 1.2199x over previous
//
#include <hip/hip_runtime.h>
#include <hip/hip_bf16.h>

#define NN 100000
#define NE 3200000
#define DH 128
#define NL 3
#define NG 64
#define BN_EPS 1e-5f
#define NEG_INF (-1e30f)

__device__ __forceinline__ void atomAddF(float* p, float v) {
    __hip_atomic_fetch_add(p, v, __ATOMIC_RELAXED, __HIP_MEMORY_SCOPE_AGENT);
}
__device__ __forceinline__ int atomAddI(int* p, int v) {
    return __hip_atomic_fetch_add(p, v, __ATOMIC_RELAXED, __HIP_MEMORY_SCOPE_AGENT);
}

__global__ void k_zero(int* __restrict__ cnt, int* __restrict__ gcounter,
                       float* __restrict__ idsc) {
    int i = blockIdx.x * 256 + threadIdx.x;
    if (i < NN) cnt[i] = 0;
    if (i == 0) *gcounter = 0;
    if (i < 2 * DH) idsc[i] = (i < DH) ? 1.0f : 0.0f;  // identity scale/shift
}

__global__ void k_count(const int* __restrict__ dst, int* __restrict__ cnt) {
    int e = blockIdx.x * 256 + threadIdx.x;
    if (e < NE) atomAddI(&cnt[dst[e]], 1);
}

__global__ void k_offsets(const int* __restrict__ cnt, int* __restrict__ off,
                          int* __restrict__ cursor, float* __restrict__ dinv,
                          int* __restrict__ gcounter) {
    int i = blockIdx.x * 256 + threadIdx.x;
    if (i >= NN) return;
    int c = cnt[i];
    int o = atomAddI(gcounter, c);
    off[i] = o;
    cursor[i] = o;
    dinv[i] = rsqrtf((float)c + 1.0f);
}

__global__ void k_permute(const int* __restrict__ src, const int* __restrict__ dst,
                          const float* __restrict__ dinv, int* __restrict__ cursor,
                          int2* __restrict__ edata) {
    int e = blockIdx.x * 256 + threadIdx.x;
    if (e >= NE) return;
    int s = src[e], d = dst[e];
    int pos = atomAddI(&cursor[d], 1);
    edata[pos] = make_int2(s, __float_as_int(dinv[s]));
}

__global__ void k_starts(const int* __restrict__ batch, int* __restrict__ starts) {
    int i = blockIdx.x * 256 + threadIdx.x;
    if (i >= NN) return;
    int g  = batch[i];
    int gp = (i == 0) ? -1 : batch[i - 1];
    for (int gg = gp + 1; gg <= g; ++gg) starts[gg] = i;
    if (i == NN - 1) {
        for (int gg = g + 1; gg <= NG; ++gg) starts[gg] = NN;
    }
}

// One wave per dst node; applies previous layer's BN+ReLU (scale/shift/lo) to each
// gathered element on the fly. S[d] = dinv[d]*sum dinv[s]*f(X[s]) + dinv[d]^2*f(X[d])
__global__ __launch_bounds__(256) void k_aggregate(const float* __restrict__ X,
        const int2* __restrict__ ed, const int* __restrict__ off,
        const int* __restrict__ cnt, const float* __restrict__ dinv,
        const float* __restrict__ SC, float lo,
        float* __restrict__ S, float* __restrict__ stats) {
    if (blockIdx.x == 0 && threadIdx.x < 256) stats[threadIdx.x] = 0.0f;
    int w = (blockIdx.x << 2) + (threadIdx.x >> 6);  // 4 waves/block
    if (w >= NN) return;
    int lane = threadIdx.x & 63;
    int o = __builtin_amdgcn_readfirstlane(off[w]);
    int n = __builtin_amdgcn_readfirstlane(cnt[w]);
    const int2* e = ed + o;
    int col = lane << 1;
    float2 sc = *(const float2*)&SC[col];
    float2 sh = *(const float2*)&SC[DH + col];
    float ax = 0.0f, ay = 0.0f;
    int j = 0;
    for (; j + 4 <= n; j += 4) {
        int2 e0 = e[j], e1 = e[j + 1], e2 = e[j + 2], e3 = e[j + 3];
        float2 v0 = *(const float2*)&X[(size_t)e0.x * DH + col];
        float2 v1 = *(const float2*)&X[(size_t)e1.x * DH + col];
        float2 v2 = *(const float2*)&X[(size_t)e2.x * DH + col];
        float2 v3 = *(const float2*)&X[(size_t)e3.x * DH + col];
        float w0 = __int_as_float(e0.y), w1 = __int_as_float(e1.y);
        float w2 = __int_as_float(e2.y), w3 = __int_as_float(e3.y);
        ax = fmaf(w0, fmaxf(fmaf(v0.x, sc.x, sh.x), lo), ax);
        ay = fmaf(w0, fmaxf(fmaf(v0.y, sc.y, sh.y), lo), ay);
        ax = fmaf(w1, fmaxf(fmaf(v1.x, sc.x, sh.x), lo), ax);
        ay = fmaf(w1, fmaxf(fmaf(v1.y, sc.y, sh.y), lo), ay);
        ax = fmaf(w2, fmaxf(fmaf(v2.x, sc.x, sh.x), lo), ax);
        ay = fmaf(w2, fmaxf(fmaf(v2.y, sc.y, sh.y), lo), ay);
        ax = fmaf(w3, fmaxf(fmaf(v3.x, sc.x, sh.x), lo), ax);
        ay = fmaf(w3, fmaxf(fmaf(v3.y, sc.y, sh.y), lo), ay);
    }
    for (; j < n; ++j) {
        int2 e0 = e[j];
        float2 v0 = *(const float2*)&X[(size_t)e0.x * DH + col];
        float w0 = __int_as_float(e0.y);
        ax = fmaf(w0, fmaxf(fmaf(v0.x, sc.x, sh.x), lo), ax);
        ay = fmaf(w0, fmaxf(fmaf(v0.y, sc.y, sh.y), lo), ay);
    }
    float di = dinv[w];
    float2 sv = *(const float2*)&X[(size_t)w * DH + col];
    float svx = fmaxf(fmaf(sv.x, sc.x, sh.x), lo);
    float svy = fmaxf(fmaf(sv.y, sc.y, sh.y), lo);
    float2 out;
    out.x = fmaf(di, ax, di * di * svx);
    out.y = fmaf(di, ay, di * di * svy);
    *(float2*)&S[(size_t)w * DH + col] = out;
}

// Register-tiled GEMM: block = 64 rows x 128 cols, thread = 8 rows x 4 cols.
// W (128x128 f32 = 64KB) in LDS. BN stats block-reduced in LDS, then 256 atomics/block.
__global__ __launch_bounds__(256) void k_gemm_stats(const float* __restrict__ X,
                                                    const float* __restrict__ W,
                                                    float* __restrict__ Y,
                                                    float* __restrict__ stats) {
    __shared__ float4 wlds[DH * 32];  // 64 KB, [k][cg]
    int t = threadIdx.x;
    const float4* W4 = (const float4*)W;
    for (int i = t; i < DH * 32; i += 256) wlds[i] = W4[i];
    __syncthreads();
    int cg = t & 31, rg = t >> 5;
    int row0 = blockIdx.x * 64 + rg * 8;
    bool full = (row0 + 8 <= NN);
    float a[8][4] = {};
    for (int k = 0; k < DH; k += 4) {
        float4 xv[8];
#pragma unroll
        for (int i = 0; i < 8; ++i) {
            int r = row0 + i;
            if (full || r < NN)
                xv[i] = *(const float4*)&X[(size_t)r * DH + k];
            else
                xv[i] = make_float4(0.f, 0.f, 0.f, 0.f);
        }
#pragma unroll
        for (int kk = 0; kk < 4; ++kk) {
            float4 w4 = wlds[((k + kk) << 5) + cg];
#pragma unroll
            for (int i = 0; i < 8; ++i) {
                float xs = (kk == 0) ? xv[i].x : (kk == 1) ? xv[i].y
                         : (kk == 2) ? xv[i].z : xv[i].w;
                a[i][0] = fmaf(xs, w4.x, a[i][0]);
                a[i][1] = fmaf(xs, w4.y, a[i][1]);
                a[i][2] = fmaf(xs, w4.z, a[i][2]);
                a[i][3] = fmaf(xs, w4.w, a[i][3]);
            }
        }
    }
    float ps[4] = {}, q[4] = {};
    int c = cg << 2;
#pragma unroll
    for (int i = 0; i < 8; ++i) {
        int r = row0 + i;
        if (r < NN) {
            float4 o = {a[i][0], a[i][1], a[i][2], a[i][3]};
            *(float4*)&Y[(size_t)r * DH + c] = o;
            ps[0] += a[i][0]; ps[1] += a[i][1]; ps[2] += a[i][2]; ps[3] += a[i][3];
            q[0] = fmaf(a[i][0], a[i][0], q[0]); q[1] = fmaf(a[i][1], a[i][1], q[1]);
            q[2] = fmaf(a[i][2], a[i][2], q[2]); q[3] = fmaf(a[i][3], a[i][3], q[3]);
        }
    }
    __syncthreads();  // done reading wlds; reuse as reduction scratch
    float* red = (float*)wlds;
    int base = t * 8;
    red[base + 0] = ps[0]; red[base + 1] = ps[1]; red[base + 2] = ps[2]; red[base + 3] = ps[3];
    red[base + 4] = q[0];  red[base + 5] = q[1];  red[base + 6] = q[2];  red[base + 7] = q[3];
    __syncthreads();
    if (t < 32) {
        float s[8] = {};
        for (int g2 = 0; g2 < 8; ++g2) {
            int b2 = (g2 * 32 + t) * 8;
#pragma unroll
            for (int j = 0; j < 8; ++j) s[j] += red[b2 + j];
        }
        int cc = t << 2;
        atomAddF(&stats[cc + 0], s[0]); atomAddF(&stats[cc + 1], s[1]);
        atomAddF(&stats[cc + 2], s[2]); atomAddF(&stats[cc + 3], s[3]);
        atomAddF(&stats[DH + cc + 0], s[4]); atomAddF(&stats[DH + cc + 1], s[5]);
        atomAddF(&stats[DH + cc + 2], s[6]); atomAddF(&stats[DH + cc + 3], s[7]);
    }
}

// stats -> per-channel scale/shift for fused BN
__global__ void k_bnprep(const float* __restrict__ stats, const float* __restrict__ gamma,
                         const float* __restrict__ beta, float* __restrict__ SC) {
    int j = threadIdx.x;
    if (j >= DH) return;
    const float inv_n = 1.0f / NN;
    float mean = stats[j] * inv_n;
    float var  = stats[DH + j] * inv_n - mean * mean;
    float s    = gamma[j] * rsqrtf(var + BN_EPS);
    SC[j] = s;
    SC[DH + j] = beta[j] - mean * s;
}

// mean-pool with final layer's BN+ReLU applied inline
__global__ void k_pool(const float* __restrict__ H, const int* __restrict__ starts,
                       const float* __restrict__ SC, float* __restrict__ pooled) {
    int g = blockIdx.x;
    int f = threadIdx.x;  // 128
    float sc = SC[f], sh = SC[DH + f];
    int s = starts[g], e = starts[g + 1];
    float acc = 0.0f;
    for (int r = s; r < e; ++r)
        acc += fmaxf(fmaf(H[(size_t)r * DH + f], sc, sh), 0.0f);
    pooled[(g << 7) + f] = acc / fmaxf((float)(e - s), 1.0f);
}

__global__ void k_mlp(const float* __restrict__ pooled, const float* __restrict__ w1,
                      const float* __restrict__ b1, const float* __restrict__ w2,
                      const float* __restrict__ b2, float* __restrict__ out) {
    __shared__ float hid[NG * DH];
    int t = threadIdx.x;  // 256
    for (int idx = t; idx < NG * DH; idx += 256) {
        int g = idx >> 7, j = idx & 127;
        float s = b1[j];
        for (int k = 0; k < DH; ++k)
            s = fmaf(pooled[(g << 7) + k], w1[(k << 7) + j], s);
        hid[idx] = fmaxf(s, 0.0f);
    }
    __syncthreads();
    if (t < NG) {
        float s = b2[0];
        for (int j = 0; j < DH; ++j)
            s = fmaf(hid[(t << 7) + j], w2[j], s);
        out[t] = s;
    }
}

extern "C" void kernel_launch(void* const* d_in, const int* in_sizes, int n_in,
                              void* d_out, int out_size, void* d_ws, size_t ws_size,
                              hipStream_t stream) {
    const float* x      = (const float*)d_in[0];
    const int*   ei     = (const int*)d_in[1];
    const int*   batch  = (const int*)d_in[2];
    const float* conv_w = (const float*)d_in[3];
    // d_in[4] = conv_b: cancels inside BatchNorm -> unused
    const float* bn_g   = (const float*)d_in[5];
    const float* bn_b   = (const float*)d_in[6];
    const float* w1     = (const float*)d_in[7];
    const float* b1     = (const float*)d_in[8];
    const float* w2     = (const float*)d_in[9];
    const float* b2     = (const float*)d_in[10];
    const int* src = ei;
    const int* dst = ei + NE;

    float* bufA     = (float*)d_ws;                 // NN*DH
    float* bufB     = bufA + (size_t)NN * DH;       // NN*DH
    float* dinv     = bufB + (size_t)NN * DH;       // NN
    float* stats    = dinv + NN;                    // 256
    float* pooled   = stats + 256;                  // NG*DH
    int*   starts   = (int*)(pooled + NG * DH);     // 72
    int*   cnt      = starts + 72;                  // NN
    int*   off      = cnt + NN;                     // NN
    int*   cursor   = off + NN;                     // NN
    int*   gcounter = cursor + NN;                  // 8
    float* idsc     = (float*)(gcounter + 8);       // 256 (identity scale/shift)
    float* bnsc     = idsc + 256;                   // 256 (per-layer scale/shift)
    int2*  edata    = (int2*)(bnsc + 256);          // NE int2

    // one-time CSR build
    k_zero   <<<(NN + 255) / 256, 256, 0, stream>>>(cnt, gcounter, idsc);
    k_count  <<<(NE + 255) / 256, 256, 0, stream>>>(dst, cnt);
    k_offsets<<<(NN + 255) / 256, 256, 0, stream>>>(cnt, off, cursor, dinv, gcounter);
    k_permute<<<(NE + 255) / 256, 256, 0, stream>>>(src, dst, dinv, cursor, edata);
    k_starts <<<(NN + 255) / 256, 256, 0, stream>>>(batch, starts);

    const float* X  = x;
    const float* SC = idsc;
    float lo = NEG_INF;  // layer 0: no BN, no ReLU on raw input
    for (int l = 0; l < NL; ++l) {
        k_aggregate <<<25000, 256, 0, stream>>>(X, edata, off, cnt, dinv, SC, lo, bufB, stats);
        k_gemm_stats<<<(NN + 63) / 64, 256, 0, stream>>>(
            bufB, conv_w + (size_t)l * DH * DH, bufA, stats);
        k_bnprep    <<<1, 128, 0, stream>>>(stats, bn_g + l * DH, bn_b + l * DH, bnsc);
        X = bufA; SC = bnsc; lo = 0.0f;
    }
    k_pool<<<NG, DH, 0, stream>>>(bufA, starts, bnsc, pooled);
    k_mlp <<<1, 256, 0, stream>>>(pooled, w1, b1, w2, b2, (float*)d_out);
}

// Round 4
// 1768.500 us; speedup vs baseline: 10.1286x; 1.2749x over previous
//
#include <hip/hip_runtime.h>
#include <hip/hip_bf16.h>

#define NN 100000
#define NE 3200000
#define DH 128
#define NL 3
#define NG 64
#define BN_EPS 1e-5f
#define NEG_INF (-1e30f)

__device__ __forceinline__ void atomAddF(float* p, float v) {
    __hip_atomic_fetch_add(p, v, __ATOMIC_RELAXED, __HIP_MEMORY_SCOPE_AGENT);
}
__device__ __forceinline__ int atomAddI(int* p, int v) {
    return __hip_atomic_fetch_add(p, v, __ATOMIC_RELAXED, __HIP_MEMORY_SCOPE_AGENT);
}

__global__ void k_zero(int* __restrict__ cnt, int* __restrict__ gcounter,
                       float* __restrict__ idsc, float* __restrict__ psum) {
    int i = blockIdx.x * 256 + threadIdx.x;
    if (i < NN) cnt[i] = 0;
    if (i == 0) *gcounter = 0;
    if (i < 2 * DH) idsc[i] = (i < DH) ? 1.0f : 0.0f;  // identity scale/shift
    if (i < NG * DH) psum[i] = 0.0f;
}

__global__ void k_count(const int* __restrict__ dst, int* __restrict__ cnt) {
    int e = blockIdx.x * 256 + threadIdx.x;
    if (e < NE) atomAddI(&cnt[dst[e]], 1);
}

__global__ void k_offsets(const int* __restrict__ cnt, int* __restrict__ off,
                          int* __restrict__ cursor, float* __restrict__ dinv,
                          int* __restrict__ gcounter) {
    int i = blockIdx.x * 256 + threadIdx.x;
    if (i >= NN) return;
    int c = cnt[i];
    int o = atomAddI(gcounter, c);
    off[i] = o;
    cursor[i] = o;
    dinv[i] = rsqrtf((float)c + 1.0f);
}

__global__ void k_permute(const int* __restrict__ src, const int* __restrict__ dst,
                          const float* __restrict__ dinv, int* __restrict__ cursor,
                          int2* __restrict__ edata) {
    int e = blockIdx.x * 256 + threadIdx.x;
    if (e >= NE) return;
    int s = src[e], d = dst[e];
    int pos = atomAddI(&cursor[d], 1);
    edata[pos] = make_int2(s, __float_as_int(dinv[s]));
}

__global__ void k_starts(const int* __restrict__ batch, int* __restrict__ starts) {
    int i = blockIdx.x * 256 + threadIdx.x;
    if (i >= NN) return;
    int g  = batch[i];
    int gp = (i == 0) ? -1 : batch[i - 1];
    for (int gg = gp + 1; gg <= g; ++gg) starts[gg] = i;
    if (i == NN - 1) {
        for (int gg = g + 1; gg <= NG; ++gg) starts[gg] = NN;
    }
}

// One wave per dst node; applies previous layer's BN+ReLU (scale/shift/lo) to each
// gathered element on the fly. S[d] = dinv[d]*sum dinv[s]*f(X[s]) + dinv[d]^2*f(X[d])
__global__ __launch_bounds__(256) void k_aggregate(const float* __restrict__ X,
        const int2* __restrict__ ed, const int* __restrict__ off,
        const int* __restrict__ cnt, const float* __restrict__ dinv,
        const float* __restrict__ SC, float lo,
        float* __restrict__ S, float* __restrict__ stats) {
    if (blockIdx.x == 0 && threadIdx.x < 256) stats[threadIdx.x] = 0.0f;
    int w = (blockIdx.x << 2) + (threadIdx.x >> 6);  // 4 waves/block
    if (w >= NN) return;
    int lane = threadIdx.x & 63;
    int o = __builtin_amdgcn_readfirstlane(off[w]);
    int n = __builtin_amdgcn_readfirstlane(cnt[w]);
    const int2* e = ed + o;
    int col = lane << 1;
    float2 sc = *(const float2*)&SC[col];
    float2 sh = *(const float2*)&SC[DH + col];
    float ax = 0.0f, ay = 0.0f;
    int j = 0;
    for (; j + 4 <= n; j += 4) {
        int2 e0 = e[j], e1 = e[j + 1], e2 = e[j + 2], e3 = e[j + 3];
        float2 v0 = *(const float2*)&X[(size_t)e0.x * DH + col];
        float2 v1 = *(const float2*)&X[(size_t)e1.x * DH + col];
        float2 v2 = *(const float2*)&X[(size_t)e2.x * DH + col];
        float2 v3 = *(const float2*)&X[(size_t)e3.x * DH + col];
        float w0 = __int_as_float(e0.y), w1 = __int_as_float(e1.y);
        float w2 = __int_as_float(e2.y), w3 = __int_as_float(e3.y);
        ax = fmaf(w0, fmaxf(fmaf(v0.x, sc.x, sh.x), lo), ax);
        ay = fmaf(w0, fmaxf(fmaf(v0.y, sc.y, sh.y), lo), ay);
        ax = fmaf(w1, fmaxf(fmaf(v1.x, sc.x, sh.x), lo), ax);
        ay = fmaf(w1, fmaxf(fmaf(v1.y, sc.y, sh.y), lo), ay);
        ax = fmaf(w2, fmaxf(fmaf(v2.x, sc.x, sh.x), lo), ax);
        ay = fmaf(w2, fmaxf(fmaf(v2.y, sc.y, sh.y), lo), ay);
        ax = fmaf(w3, fmaxf(fmaf(v3.x, sc.x, sh.x), lo), ax);
        ay = fmaf(w3, fmaxf(fmaf(v3.y, sc.y, sh.y), lo), ay);
    }
    for (; j < n; ++j) {
        int2 e0 = e[j];
        float2 v0 = *(const float2*)&X[(size_t)e0.x * DH + col];
        float w0 = __int_as_float(e0.y);
        ax = fmaf(w0, fmaxf(fmaf(v0.x, sc.x, sh.x), lo), ax);
        ay = fmaf(w0, fmaxf(fmaf(v0.y, sc.y, sh.y), lo), ay);
    }
    float di = dinv[w];
    float2 sv = *(const float2*)&X[(size_t)w * DH + col];
    float svx = fmaxf(fmaf(sv.x, sc.x, sh.x), lo);
    float svy = fmaxf(fmaf(sv.y, sc.y, sh.y), lo);
    float2 out;
    out.x = fmaf(di, ax, di * di * svx);
    out.y = fmaf(di, ay, di * di * svy);
    *(float2*)&S[(size_t)w * DH + col] = out;
}

// Register-tiled GEMM: block = 64 rows x 128 cols, thread = 8 rows x 4 cols.
// W (128x128 f32 = 64KB) in LDS. BN stats block-reduced in LDS, then 256 atomics/block.
__global__ __launch_bounds__(256) void k_gemm_stats(const float* __restrict__ X,
                                                    const float* __restrict__ W,
                                                    float* __restrict__ Y,
                                                    float* __restrict__ stats) {
    __shared__ float4 wlds[DH * 32];  // 64 KB, [k][cg]
    int t = threadIdx.x;
    const float4* W4 = (const float4*)W;
    for (int i = t; i < DH * 32; i += 256) wlds[i] = W4[i];
    __syncthreads();
    int cg = t & 31, rg = t >> 5;
    int row0 = blockIdx.x * 64 + rg * 8;
    bool full = (row0 + 8 <= NN);
    float a[8][4] = {};
    for (int k = 0; k < DH; k += 4) {
        float4 xv[8];
#pragma unroll
        for (int i = 0; i < 8; ++i) {
            int r = row0 + i;
            if (full || r < NN)
                xv[i] = *(const float4*)&X[(size_t)r * DH + k];
            else
                xv[i] = make_float4(0.f, 0.f, 0.f, 0.f);
        }
#pragma unroll
        for (int kk = 0; kk < 4; ++kk) {
            float4 w4 = wlds[((k + kk) << 5) + cg];
#pragma unroll
            for (int i = 0; i < 8; ++i) {
                float xs = (kk == 0) ? xv[i].x : (kk == 1) ? xv[i].y
                         : (kk == 2) ? xv[i].z : xv[i].w;
                a[i][0] = fmaf(xs, w4.x, a[i][0]);
                a[i][1] = fmaf(xs, w4.y, a[i][1]);
                a[i][2] = fmaf(xs, w4.z, a[i][2]);
                a[i][3] = fmaf(xs, w4.w, a[i][3]);
            }
        }
    }
    float ps[4] = {}, q[4] = {};
    int c = cg << 2;
#pragma unroll
    for (int i = 0; i < 8; ++i) {
        int r = row0 + i;
        if (r < NN) {
            float4 o = {a[i][0], a[i][1], a[i][2], a[i][3]};
            *(float4*)&Y[(size_t)r * DH + c] = o;
            ps[0] += a[i][0]; ps[1] += a[i][1]; ps[2] += a[i][2]; ps[3] += a[i][3];
            q[0] = fmaf(a[i][0], a[i][0], q[0]); q[1] = fmaf(a[i][1], a[i][1], q[1]);
            q[2] = fmaf(a[i][2], a[i][2], q[2]); q[3] = fmaf(a[i][3], a[i][3], q[3]);
        }
    }
    __syncthreads();  // done reading wlds; reuse as reduction scratch
    float* red = (float*)wlds;
    int base = t * 8;
    red[base + 0] = ps[0]; red[base + 1] = ps[1]; red[base + 2] = ps[2]; red[base + 3] = ps[3];
    red[base + 4] = q[0];  red[base + 5] = q[1];  red[base + 6] = q[2];  red[base + 7] = q[3];
    __syncthreads();
    if (t < 32) {
        float s[8] = {};
        for (int g2 = 0; g2 < 8; ++g2) {
            int b2 = (g2 * 32 + t) * 8;
#pragma unroll
            for (int j = 0; j < 8; ++j) s[j] += red[b2 + j];
        }
        int cc = t << 2;
        atomAddF(&stats[cc + 0], s[0]); atomAddF(&stats[cc + 1], s[1]);
        atomAddF(&stats[cc + 2], s[2]); atomAddF(&stats[cc + 3], s[3]);
        atomAddF(&stats[DH + cc + 0], s[4]); atomAddF(&stats[DH + cc + 1], s[5]);
        atomAddF(&stats[DH + cc + 2], s[6]); atomAddF(&stats[DH + cc + 3], s[7]);
    }
}

// stats -> per-channel scale/shift for fused BN
__global__ void k_bnprep(const float* __restrict__ stats, const float* __restrict__ gamma,
                         const float* __restrict__ beta, float* __restrict__ SC) {
    int j = threadIdx.x;
    if (j >= DH) return;
    const float inv_n = 1.0f / NN;
    float mean = stats[j] * inv_n;
    float var  = stats[DH + j] * inv_n - mean * mean;
    float s    = gamma[j] * rsqrtf(var + BN_EPS);
    SC[j] = s;
    SC[DH + j] = beta[j] - mean * s;
}

// Parallel pool: 782 blocks x 128 rows each; BN+ReLU inline; atomic flush at
// graph boundaries only (batch is sorted -> ~1-2 flushes per thread).
__global__ __launch_bounds__(128) void k_pool_partial(const float* __restrict__ H,
        const int* __restrict__ batch, const float* __restrict__ SC,
        float* __restrict__ psum) {
    __shared__ int bsh[128];
    int t = threadIdx.x;
    int row0 = blockIdx.x * 128;
    int rl = row0 + t;
    bsh[t] = batch[rl < NN ? rl : (NN - 1)];
    __syncthreads();
    int ro = t >> 5;          // row phase 0..3
    int c  = (t & 31) << 2;   // col group
    float4 sc = *(const float4*)&SC[c];
    float4 sh = *(const float4*)&SC[DH + c];
    int nrows = NN - row0; if (nrows > 128) nrows = 128;
    float4 acc = make_float4(0.f, 0.f, 0.f, 0.f);
    int cur = -1;
    for (int rr = ro; rr < nrows; rr += 4) {
        int g = bsh[rr];
        if (g != cur) {
            if (cur >= 0) {
                float* p = &psum[(cur << 7) + c];
                atomAddF(p + 0, acc.x); atomAddF(p + 1, acc.y);
                atomAddF(p + 2, acc.z); atomAddF(p + 3, acc.w);
            }
            acc = make_float4(0.f, 0.f, 0.f, 0.f);
            cur = g;
        }
        float4 v = *(const float4*)&H[(size_t)(row0 + rr) * DH + c];
        acc.x += fmaxf(fmaf(v.x, sc.x, sh.x), 0.0f);
        acc.y += fmaxf(fmaf(v.y, sc.y, sh.y), 0.0f);
        acc.z += fmaxf(fmaf(v.z, sc.z, sh.z), 0.0f);
        acc.w += fmaxf(fmaf(v.w, sc.w, sh.w), 0.0f);
    }
    if (cur >= 0) {
        float* p = &psum[(cur << 7) + c];
        atomAddF(p + 0, acc.x); atomAddF(p + 1, acc.y);
        atomAddF(p + 2, acc.z); atomAddF(p + 3, acc.w);
    }
}

// One block per graph: divide by count, hidden GEMV, reduce to scalar output.
__global__ __launch_bounds__(128) void k_mlp(const float* __restrict__ psum,
        const int* __restrict__ starts, const float* __restrict__ w1,
        const float* __restrict__ b1, const float* __restrict__ w2,
        const float* __restrict__ b2, float* __restrict__ out) {
    __shared__ float pl[DH];
    __shared__ float red[DH];
    int g = blockIdx.x, j = threadIdx.x;  // 128 threads
    float cnt = fmaxf((float)(starts[g + 1] - starts[g]), 1.0f);
    pl[j] = psum[(g << 7) + j] / cnt;
    __syncthreads();
    float s = b1[j];
#pragma unroll 8
    for (int k = 0; k < DH; ++k)
        s = fmaf(pl[k], w1[(k << 7) + j], s);
    red[j] = fmaxf(s, 0.0f) * w2[j];
    __syncthreads();
    for (int st = 64; st > 0; st >>= 1) {
        if (j < st) red[j] += red[j + st];
        __syncthreads();
    }
    if (j == 0) out[g] = red[0] + b2[0];
}

extern "C" void kernel_launch(void* const* d_in, const int* in_sizes, int n_in,
                              void* d_out, int out_size, void* d_ws, size_t ws_size,
                              hipStream_t stream) {
    const float* x      = (const float*)d_in[0];
    const int*   ei     = (const int*)d_in[1];
    const int*   batch  = (const int*)d_in[2];
    const float* conv_w = (const float*)d_in[3];
    // d_in[4] = conv_b: cancels inside BatchNorm -> unused
    const float* bn_g   = (const float*)d_in[5];
    const float* bn_b   = (const float*)d_in[6];
    const float* w1     = (const float*)d_in[7];
    const float* b1     = (const float*)d_in[8];
    const float* w2     = (const float*)d_in[9];
    const float* b2     = (const float*)d_in[10];
    const int* src = ei;
    const int* dst = ei + NE;

    float* bufA     = (float*)d_ws;                 // NN*DH
    float* bufB     = bufA + (size_t)NN * DH;       // NN*DH
    float* dinv     = bufB + (size_t)NN * DH;       // NN
    float* stats    = dinv + NN;                    // 256
    float* psum     = stats + 256;                  // NG*DH (pool partial sums)
    int*   starts   = (int*)(psum + NG * DH);       // 72
    int*   cnt      = starts + 72;                  // NN
    int*   off      = cnt + NN;                     // NN
    int*   cursor   = off + NN;                     // NN
    int*   gcounter = cursor + NN;                  // 8
    float* idsc     = (float*)(gcounter + 8);       // 256 (identity scale/shift)
    float* bnsc     = idsc + 256;                   // 256 (per-layer scale/shift)
    int2*  edata    = (int2*)(bnsc + 256);          // NE int2

    // one-time CSR build (+ zeroing of accumulators)
    k_zero   <<<(NN + 255) / 256, 256, 0, stream>>>(cnt, gcounter, idsc, psum);
    k_count  <<<(NE + 255) / 256, 256, 0, stream>>>(dst, cnt);
    k_offsets<<<(NN + 255) / 256, 256, 0, stream>>>(cnt, off, cursor, dinv, gcounter);
    k_permute<<<(NE + 255) / 256, 256, 0, stream>>>(src, dst, dinv, cursor, edata);
    k_starts <<<(NN + 255) / 256, 256, 0, stream>>>(batch, starts);

    const float* X  = x;
    const float* SC = idsc;
    float lo = NEG_INF;  // layer 0: no BN, no ReLU on raw input
    for (int l = 0; l < NL; ++l) {
        k_aggregate <<<25000, 256, 0, stream>>>(X, edata, off, cnt, dinv, SC, lo, bufB, stats);
        k_gemm_stats<<<(NN + 63) / 64, 256, 0, stream>>>(
            bufB, conv_w + (size_t)l * DH * DH, bufA, stats);
        k_bnprep    <<<1, 128, 0, stream>>>(stats, bn_g + l * DH, bn_b + l * DH, bnsc);
        X = bufA; SC = bnsc; lo = 0.0f;
    }
    k_pool_partial<<<(NN + 127) / 128, 128, 0, stream>>>(bufA, batch, bnsc, psum);
    k_mlp<<<NG, 128, 0, stream>>>(psum, starts, w1, b1, w2, b2, (float*)d_out);
}

// Round 5
// 1564.595 us; speedup vs baseline: 11.4486x; 1.1303x over previous
//
#include <hip/hip_runtime.h>
#include <hip/hip_bf16.h>

#define NN 100000
#define NE 3200000
#define DH 128
#define NL 3
#define NG 64
#define BN_EPS 1e-5f
#define NEG_INF (-1e30f)

__device__ __forceinline__ void atomAddF(float* p, float v) {
    __hip_atomic_fetch_add(p, v, __ATOMIC_RELAXED, __HIP_MEMORY_SCOPE_AGENT);
}
__device__ __forceinline__ int atomAddI(int* p, int v) {
    return __hip_atomic_fetch_add(p, v, __ATOMIC_RELAXED, __HIP_MEMORY_SCOPE_AGENT);
}

__global__ void k_zero(int* __restrict__ cnt, int* __restrict__ gcounter,
                       float* __restrict__ idsc, float* __restrict__ psum) {
    int i = blockIdx.x * 256 + threadIdx.x;
    if (i < NN) cnt[i] = 0;
    if (i == 0) *gcounter = 0;
    if (i < 2 * DH) idsc[i] = (i < DH) ? 1.0f : 0.0f;  // identity scale/shift
    if (i < NG * DH) psum[i] = 0.0f;
}

__global__ void k_count(const int* __restrict__ dst, int* __restrict__ cnt) {
    int e = blockIdx.x * 256 + threadIdx.x;
    if (e < NE) atomAddI(&cnt[dst[e]], 1);
}

__global__ void k_offsets(const int* __restrict__ cnt, int* __restrict__ off,
                          int* __restrict__ cursor, float* __restrict__ dinv,
                          int* __restrict__ gcounter) {
    int i = blockIdx.x * 256 + threadIdx.x;
    if (i >= NN) return;
    int c = cnt[i];
    int o = atomAddI(gcounter, c);
    off[i] = o;
    cursor[i] = o;
    dinv[i] = rsqrtf((float)c + 1.0f);
}

__global__ void k_permute(const int* __restrict__ src, const int* __restrict__ dst,
                          const float* __restrict__ dinv, int* __restrict__ cursor,
                          int2* __restrict__ edata) {
    int e = blockIdx.x * 256 + threadIdx.x;
    if (e >= NE) return;
    int s = src[e], d = dst[e];
    int pos = atomAddI(&cursor[d], 1);
    edata[pos] = make_int2(s, __float_as_int(dinv[s]));
}

__global__ void k_starts(const int* __restrict__ batch, int* __restrict__ starts) {
    int i = blockIdx.x * 256 + threadIdx.x;
    if (i >= NN) return;
    int g  = batch[i];
    int gp = (i == 0) ? -1 : batch[i - 1];
    for (int gg = gp + 1; gg <= g; ++gg) starts[gg] = i;
    if (i == NN - 1) {
        for (int gg = g + 1; gg <= NG; ++gg) starts[gg] = NN;
    }
}

// One wave per dst node; applies previous layer's BN+ReLU (scale/shift/lo) to each
// gathered element on the fly. S[d] = dinv[d]*sum dinv[s]*f(X[s]) + dinv[d]^2*f(X[d])
__global__ __launch_bounds__(256) void k_aggregate(const float* __restrict__ X,
        const int2* __restrict__ ed, const int* __restrict__ off,
        const int* __restrict__ cnt, const float* __restrict__ dinv,
        const float* __restrict__ SC, float lo,
        float* __restrict__ S, float* __restrict__ stats) {
    if (blockIdx.x == 0 && threadIdx.x < 256) stats[threadIdx.x] = 0.0f;
    int w = (blockIdx.x << 2) + (threadIdx.x >> 6);  // 4 waves/block
    if (w >= NN) return;
    int lane = threadIdx.x & 63;
    int o = __builtin_amdgcn_readfirstlane(off[w]);
    int n = __builtin_amdgcn_readfirstlane(cnt[w]);
    const int2* e = ed + o;
    int col = lane << 1;
    float2 sc = *(const float2*)&SC[col];
    float2 sh = *(const float2*)&SC[DH + col];
    float ax = 0.0f, ay = 0.0f;
    int j = 0;
    for (; j + 4 <= n; j += 4) {
        int2 e0 = e[j], e1 = e[j + 1], e2 = e[j + 2], e3 = e[j + 3];
        float2 v0 = *(const float2*)&X[(size_t)e0.x * DH + col];
        float2 v1 = *(const float2*)&X[(size_t)e1.x * DH + col];
        float2 v2 = *(const float2*)&X[(size_t)e2.x * DH + col];
        float2 v3 = *(const float2*)&X[(size_t)e3.x * DH + col];
        float w0 = __int_as_float(e0.y), w1 = __int_as_float(e1.y);
        float w2 = __int_as_float(e2.y), w3 = __int_as_float(e3.y);
        ax = fmaf(w0, fmaxf(fmaf(v0.x, sc.x, sh.x), lo), ax);
        ay = fmaf(w0, fmaxf(fmaf(v0.y, sc.y, sh.y), lo), ay);
        ax = fmaf(w1, fmaxf(fmaf(v1.x, sc.x, sh.x), lo), ax);
        ay = fmaf(w1, fmaxf(fmaf(v1.y, sc.y, sh.y), lo), ay);
        ax = fmaf(w2, fmaxf(fmaf(v2.x, sc.x, sh.x), lo), ax);
        ay = fmaf(w2, fmaxf(fmaf(v2.y, sc.y, sh.y), lo), ay);
        ax = fmaf(w3, fmaxf(fmaf(v3.x, sc.x, sh.x), lo), ax);
        ay = fmaf(w3, fmaxf(fmaf(v3.y, sc.y, sh.y), lo), ay);
    }
    for (; j < n; ++j) {
        int2 e0 = e[j];
        float2 v0 = *(const float2*)&X[(size_t)e0.x * DH + col];
        float w0 = __int_as_float(e0.y);
        ax = fmaf(w0, fmaxf(fmaf(v0.x, sc.x, sh.x), lo), ax);
        ay = fmaf(w0, fmaxf(fmaf(v0.y, sc.y, sh.y), lo), ay);
    }
    float di = dinv[w];
    float2 sv = *(const float2*)&X[(size_t)w * DH + col];
    float svx = fmaxf(fmaf(sv.x, sc.x, sh.x), lo);
    float svy = fmaxf(fmaf(sv.y, sc.y, sh.y), lo);
    float2 out;
    out.x = fmaf(di, ax, di * di * svx);
    out.y = fmaf(di, ay, di * di * svy);
    *(float2*)&S[(size_t)w * DH + col] = out;
}

// Register-tiled GEMM v2: X tile (64 rows x 128 cols = 32KB) in LDS, W from
// global (L1/L2-resident, broadcast loads). 32KB LDS -> 5 blocks/CU.
// Thread = 8 rows x 4 cols. BN stats block-reduced in LDS scratch (reused).
__global__ __launch_bounds__(256) void k_gemm_stats(const float* __restrict__ X,
                                                    const float* __restrict__ W,
                                                    float* __restrict__ Y,
                                                    float* __restrict__ stats) {
    __shared__ float4 xl4[64 * 32];  // 32 KB: [row][kgroup]
    int t = threadIdx.x;
    int row0 = blockIdx.x * 64;
    // coalesced stage; rows >= NN read garbage from our own ws (X is always
    // bufB, which has >32KB of ws after it) and are never used.
    const float4* Xv = (const float4*)(X + (size_t)row0 * DH);
#pragma unroll
    for (int i = 0; i < 8; ++i) xl4[t + i * 256] = Xv[t + i * 256];
    __syncthreads();
    int cg = t & 31, rg = t >> 5;
    const float4* W4 = (const float4*)W;
    float a[8][4] = {};
    for (int k = 0; k < DH; k += 4) {
        float4 w0 = W4[((k + 0) << 5) + cg];
        float4 w1 = W4[((k + 1) << 5) + cg];
        float4 w2 = W4[((k + 2) << 5) + cg];
        float4 w3 = W4[((k + 3) << 5) + cg];
#pragma unroll
        for (int i = 0; i < 8; ++i) {
            float4 xv = xl4[((rg * 8 + i) << 5) + (k >> 2)];  // wave-broadcast
            a[i][0] = fmaf(xv.x, w0.x, a[i][0]);
            a[i][0] = fmaf(xv.y, w1.x, a[i][0]);
            a[i][0] = fmaf(xv.z, w2.x, a[i][0]);
            a[i][0] = fmaf(xv.w, w3.x, a[i][0]);
            a[i][1] = fmaf(xv.x, w0.y, a[i][1]);
            a[i][1] = fmaf(xv.y, w1.y, a[i][1]);
            a[i][1] = fmaf(xv.z, w2.y, a[i][1]);
            a[i][1] = fmaf(xv.w, w3.y, a[i][1]);
            a[i][2] = fmaf(xv.x, w0.z, a[i][2]);
            a[i][2] = fmaf(xv.y, w1.z, a[i][2]);
            a[i][2] = fmaf(xv.z, w2.z, a[i][2]);
            a[i][2] = fmaf(xv.w, w3.z, a[i][2]);
            a[i][3] = fmaf(xv.x, w0.w, a[i][3]);
            a[i][3] = fmaf(xv.y, w1.w, a[i][3]);
            a[i][3] = fmaf(xv.z, w2.w, a[i][3]);
            a[i][3] = fmaf(xv.w, w3.w, a[i][3]);
        }
    }
    int rbase = row0 + rg * 8;
    float ps[4] = {}, q[4] = {};
    int c = cg << 2;
#pragma unroll
    for (int i = 0; i < 8; ++i) {
        int r = rbase + i;
        if (r < NN) {
            float4 o = {a[i][0], a[i][1], a[i][2], a[i][3]};
            *(float4*)&Y[(size_t)r * DH + c] = o;
            ps[0] += a[i][0]; ps[1] += a[i][1]; ps[2] += a[i][2]; ps[3] += a[i][3];
            q[0] = fmaf(a[i][0], a[i][0], q[0]); q[1] = fmaf(a[i][1], a[i][1], q[1]);
            q[2] = fmaf(a[i][2], a[i][2], q[2]); q[3] = fmaf(a[i][3], a[i][3], q[3]);
        }
    }
    __syncthreads();  // done reading xl4; reuse as reduction scratch (8KB)
    float* red = (float*)xl4;
    int base = t * 8;
    red[base + 0] = ps[0]; red[base + 1] = ps[1]; red[base + 2] = ps[2]; red[base + 3] = ps[3];
    red[base + 4] = q[0];  red[base + 5] = q[1];  red[base + 6] = q[2];  red[base + 7] = q[3];
    __syncthreads();
    if (t < 32) {
        float s[8] = {};
        for (int g2 = 0; g2 < 8; ++g2) {
            int b2 = (g2 * 32 + t) * 8;
#pragma unroll
            for (int j = 0; j < 8; ++j) s[j] += red[b2 + j];
        }
        int cc = t << 2;
        atomAddF(&stats[cc + 0], s[0]); atomAddF(&stats[cc + 1], s[1]);
        atomAddF(&stats[cc + 2], s[2]); atomAddF(&stats[cc + 3], s[3]);
        atomAddF(&stats[DH + cc + 0], s[4]); atomAddF(&stats[DH + cc + 1], s[5]);
        atomAddF(&stats[DH + cc + 2], s[6]); atomAddF(&stats[DH + cc + 3], s[7]);
    }
}

// stats -> per-channel scale/shift for fused BN
__global__ void k_bnprep(const float* __restrict__ stats, const float* __restrict__ gamma,
                         const float* __restrict__ beta, float* __restrict__ SC) {
    int j = threadIdx.x;
    if (j >= DH) return;
    const float inv_n = 1.0f / NN;
    float mean = stats[j] * inv_n;
    float var  = stats[DH + j] * inv_n - mean * mean;
    float s    = gamma[j] * rsqrtf(var + BN_EPS);
    SC[j] = s;
    SC[DH + j] = beta[j] - mean * s;
}

// Parallel pool: 782 blocks x 128 rows each; BN+ReLU inline; atomic flush at
// graph boundaries only (batch is sorted -> ~1-2 flushes per thread).
__global__ __launch_bounds__(128) void k_pool_partial(const float* __restrict__ H,
        const int* __restrict__ batch, const float* __restrict__ SC,
        float* __restrict__ psum) {
    __shared__ int bsh[128];
    int t = threadIdx.x;
    int row0 = blockIdx.x * 128;
    int rl = row0 + t;
    bsh[t] = batch[rl < NN ? rl : (NN - 1)];
    __syncthreads();
    int ro = t >> 5;          // row phase 0..3
    int c  = (t & 31) << 2;   // col group
    float4 sc = *(const float4*)&SC[c];
    float4 sh = *(const float4*)&SC[DH + c];
    int nrows = NN - row0; if (nrows > 128) nrows = 128;
    float4 acc = make_float4(0.f, 0.f, 0.f, 0.f);
    int cur = -1;
    for (int rr = ro; rr < nrows; rr += 4) {
        int g = bsh[rr];
        if (g != cur) {
            if (cur >= 0) {
                float* p = &psum[(cur << 7) + c];
                atomAddF(p + 0, acc.x); atomAddF(p + 1, acc.y);
                atomAddF(p + 2, acc.z); atomAddF(p + 3, acc.w);
            }
            acc = make_float4(0.f, 0.f, 0.f, 0.f);
            cur = g;
        }
        float4 v = *(const float4*)&H[(size_t)(row0 + rr) * DH + c];
        acc.x += fmaxf(fmaf(v.x, sc.x, sh.x), 0.0f);
        acc.y += fmaxf(fmaf(v.y, sc.y, sh.y), 0.0f);
        acc.z += fmaxf(fmaf(v.z, sc.z, sh.z), 0.0f);
        acc.w += fmaxf(fmaf(v.w, sc.w, sh.w), 0.0f);
    }
    if (cur >= 0) {
        float* p = &psum[(cur << 7) + c];
        atomAddF(p + 0, acc.x); atomAddF(p + 1, acc.y);
        atomAddF(p + 2, acc.z); atomAddF(p + 3, acc.w);
    }
}

// One block per graph: divide by count, hidden GEMV, reduce to scalar output.
__global__ __launch_bounds__(128) void k_mlp(const float* __restrict__ psum,
        const int* __restrict__ starts, const float* __restrict__ w1,
        const float* __restrict__ b1, const float* __restrict__ w2,
        const float* __restrict__ b2, float* __restrict__ out) {
    __shared__ float pl[DH];
    __shared__ float red[DH];
    int g = blockIdx.x, j = threadIdx.x;  // 128 threads
    float cnt = fmaxf((float)(starts[g + 1] - starts[g]), 1.0f);
    pl[j] = psum[(g << 7) + j] / cnt;
    __syncthreads();
    float s = b1[j];
#pragma unroll 8
    for (int k = 0; k < DH; ++k)
        s = fmaf(pl[k], w1[(k << 7) + j], s);
    red[j] = fmaxf(s, 0.0f) * w2[j];
    __syncthreads();
    for (int st = 64; st > 0; st >>= 1) {
        if (j < st) red[j] += red[j + st];
        __syncthreads();
    }
    if (j == 0) out[g] = red[0] + b2[0];
}

extern "C" void kernel_launch(void* const* d_in, const int* in_sizes, int n_in,
                              void* d_out, int out_size, void* d_ws, size_t ws_size,
                              hipStream_t stream) {
    const float* x      = (const float*)d_in[0];
    const int*   ei     = (const int*)d_in[1];
    const int*   batch  = (const int*)d_in[2];
    const float* conv_w = (const float*)d_in[3];
    // d_in[4] = conv_b: cancels inside BatchNorm -> unused
    const float* bn_g   = (const float*)d_in[5];
    const float* bn_b   = (const float*)d_in[6];
    const float* w1     = (const float*)d_in[7];
    const float* b1     = (const float*)d_in[8];
    const float* w2     = (const float*)d_in[9];
    const float* b2     = (const float*)d_in[10];
    const int* src = ei;
    const int* dst = ei + NE;

    float* bufA     = (float*)d_ws;                 // NN*DH
    float* bufB     = bufA + (size_t)NN * DH;       // NN*DH
    float* dinv     = bufB + (size_t)NN * DH;       // NN
    float* stats    = dinv + NN;                    // 256
    float* psum     = stats + 256;                  // NG*DH (pool partial sums)
    int*   starts   = (int*)(psum + NG * DH);       // 72
    int*   cnt      = starts + 72;                  // NN
    int*   off      = cnt + NN;                     // NN
    int*   cursor   = off + NN;                     // NN
    int*   gcounter = cursor + NN;                  // 8
    float* idsc     = (float*)(gcounter + 8);       // 256 (identity scale/shift)
    float* bnsc     = idsc + 256;                   // 256 (per-layer scale/shift)
    int2*  edata    = (int2*)(bnsc + 256);          // NE int2

    // one-time CSR build (+ zeroing of accumulators)
    k_zero   <<<(NN + 255) / 256, 256, 0, stream>>>(cnt, gcounter, idsc, psum);
    k_count  <<<(NE + 255) / 256, 256, 0, stream>>>(dst, cnt);
    k_offsets<<<(NN + 255) / 256, 256, 0, stream>>>(cnt, off, cursor, dinv, gcounter);
    k_permute<<<(NE + 255) / 256, 256, 0, stream>>>(src, dst, dinv, cursor, edata);
    k_starts <<<(NN + 255) / 256, 256, 0, stream>>>(batch, starts);

    const float* X  = x;
    const float* SC = idsc;
    float lo = NEG_INF;  // layer 0: no BN, no ReLU on raw input
    for (int l = 0; l < NL; ++l) {
        k_aggregate <<<25000, 256, 0, stream>>>(X, edata, off, cnt, dinv, SC, lo, bufB, stats);
        k_gemm_stats<<<(NN + 63) / 64, 256, 0, stream>>>(
            bufB, conv_w + (size_t)l * DH * DH, bufA, stats);
        k_bnprep    <<<1, 128, 0, stream>>>(stats, bn_g + l * DH, bn_b + l * DH, bnsc);
        X = bufA; SC = bnsc; lo = 0.0f;
    }
    k_pool_partial<<<(NN + 127) / 128, 128, 0, stream>>>(bufA, batch, bnsc, psum);
    k_mlp<<<NG, 128, 0, stream>>>(psum, starts, w1, b1, w2, b2, (float*)d_out);
}

// Round 6
// 1285.525 us; speedup vs baseline: 13.9340x; 1.2171x over previous
//
#include <hip/hip_runtime.h>
#include <hip/hip_bf16.h>

#define NN 100000
#define NE 3200000
#define DH 128
#define NL 3
#define NG 64
#define BN_EPS 1e-5f
#define NEG_INF (-1e30f)

__device__ __forceinline__ void atomAddF(float* p, float v) {
    __hip_atomic_fetch_add(p, v, __ATOMIC_RELAXED, __HIP_MEMORY_SCOPE_AGENT);
}
__device__ __forceinline__ int atomAddI(int* p, int v) {
    return __hip_atomic_fetch_add(p, v, __ATOMIC_RELAXED, __HIP_MEMORY_SCOPE_AGENT);
}
// f32 -> bf16 with round-to-nearest-even
__device__ __forceinline__ unsigned short bf16rn(float f) {
    unsigned int u = __float_as_uint(f);
    u += 0x7FFFu + ((u >> 16) & 1u);
    return (unsigned short)(u >> 16);
}
__device__ __forceinline__ float bf_lo(unsigned int u) {  // low bf16 of packed pair
    return __uint_as_float(u << 16);
}
__device__ __forceinline__ float bf_hi(unsigned int u) {  // high bf16 of packed pair
    return __uint_as_float(u & 0xFFFF0000u);
}

__global__ void k_zero(int* __restrict__ cnt, int* __restrict__ gcounter,
                       float* __restrict__ idsc, float* __restrict__ psum) {
    int i = blockIdx.x * 256 + threadIdx.x;
    if (i < NN) cnt[i] = 0;
    if (i == 0) *gcounter = 0;
    if (i < 2 * DH) idsc[i] = (i < DH) ? 1.0f : 0.0f;  // identity scale/shift
    if (i < NG * DH) psum[i] = 0.0f;
}

// one-time: x (f32) -> bf16 feature buffer
__global__ void k_convert(const float* __restrict__ X, ushort4* __restrict__ XB) {
    int i = blockIdx.x * 256 + threadIdx.x;  // groups of 4 floats
    if (i >= NN * DH / 4) return;
    float4 v = ((const float4*)X)[i];
    ushort4 o;
    o.x = bf16rn(v.x); o.y = bf16rn(v.y); o.z = bf16rn(v.z); o.w = bf16rn(v.w);
    XB[i] = o;
}

__global__ void k_count(const int* __restrict__ dst, int* __restrict__ cnt) {
    int e = blockIdx.x * 256 + threadIdx.x;
    if (e < NE) atomAddI(&cnt[dst[e]], 1);
}

__global__ void k_offsets(const int* __restrict__ cnt, int* __restrict__ off,
                          int* __restrict__ cursor, float* __restrict__ dinv,
                          int* __restrict__ gcounter) {
    int i = blockIdx.x * 256 + threadIdx.x;
    if (i >= NN) return;
    int c = cnt[i];
    int o = atomAddI(gcounter, c);
    off[i] = o;
    cursor[i] = o;
    dinv[i] = rsqrtf((float)c + 1.0f);
}

__global__ void k_permute(const int* __restrict__ src, const int* __restrict__ dst,
                          const float* __restrict__ dinv, int* __restrict__ cursor,
                          int2* __restrict__ edata) {
    int e = blockIdx.x * 256 + threadIdx.x;
    if (e >= NE) return;
    int s = src[e], d = dst[e];
    int pos = atomAddI(&cursor[d], 1);
    edata[pos] = make_int2(s, __float_as_int(dinv[s]));
}

__global__ void k_starts(const int* __restrict__ batch, int* __restrict__ starts) {
    int i = blockIdx.x * 256 + threadIdx.x;
    if (i >= NN) return;
    int g  = batch[i];
    int gp = (i == 0) ? -1 : batch[i - 1];
    for (int gg = gp + 1; gg <= g; ++gg) starts[gg] = i;
    if (i == NN - 1) {
        for (int gg = g + 1; gg <= NG; ++gg) starts[gg] = NN;
    }
}

// One wave per dst node; gathers bf16 rows (4 B/lane = 2 cols), applies previous
// layer's BN+ReLU in f32 on the fly, accumulates f32, one coalesced f32 write.
__global__ __launch_bounds__(256) void k_aggregate(const unsigned short* __restrict__ XB,
        const int2* __restrict__ ed, const int* __restrict__ off,
        const int* __restrict__ cnt, const float* __restrict__ dinv,
        const float* __restrict__ SC, float lo,
        float* __restrict__ S, float* __restrict__ stats) {
    if (blockIdx.x == 0 && threadIdx.x < 256) stats[threadIdx.x] = 0.0f;
    int w = (blockIdx.x << 2) + (threadIdx.x >> 6);  // 4 waves/block
    if (w >= NN) return;
    int lane = threadIdx.x & 63;
    int o = __builtin_amdgcn_readfirstlane(off[w]);
    int n = __builtin_amdgcn_readfirstlane(cnt[w]);
    const int2* e = ed + o;
    int col = lane << 1;
    float2 sc = *(const float2*)&SC[col];
    float2 sh = *(const float2*)&SC[DH + col];
    float ax = 0.0f, ay = 0.0f;
    int j = 0;
    for (; j + 4 <= n; j += 4) {
        int2 e0 = e[j], e1 = e[j + 1], e2 = e[j + 2], e3 = e[j + 3];
        unsigned int u0 = *(const unsigned int*)&XB[(size_t)e0.x * DH + col];
        unsigned int u1 = *(const unsigned int*)&XB[(size_t)e1.x * DH + col];
        unsigned int u2 = *(const unsigned int*)&XB[(size_t)e2.x * DH + col];
        unsigned int u3 = *(const unsigned int*)&XB[(size_t)e3.x * DH + col];
        float w0 = __int_as_float(e0.y), w1 = __int_as_float(e1.y);
        float w2 = __int_as_float(e2.y), w3 = __int_as_float(e3.y);
        ax = fmaf(w0, fmaxf(fmaf(bf_lo(u0), sc.x, sh.x), lo), ax);
        ay = fmaf(w0, fmaxf(fmaf(bf_hi(u0), sc.y, sh.y), lo), ay);
        ax = fmaf(w1, fmaxf(fmaf(bf_lo(u1), sc.x, sh.x), lo), ax);
        ay = fmaf(w1, fmaxf(fmaf(bf_hi(u1), sc.y, sh.y), lo), ay);
        ax = fmaf(w2, fmaxf(fmaf(bf_lo(u2), sc.x, sh.x), lo), ax);
        ay = fmaf(w2, fmaxf(fmaf(bf_hi(u2), sc.y, sh.y), lo), ay);
        ax = fmaf(w3, fmaxf(fmaf(bf_lo(u3), sc.x, sh.x), lo), ax);
        ay = fmaf(w3, fmaxf(fmaf(bf_hi(u3), sc.y, sh.y), lo), ay);
    }
    for (; j < n; ++j) {
        int2 e0 = e[j];
        unsigned int u0 = *(const unsigned int*)&XB[(size_t)e0.x * DH + col];
        float w0 = __int_as_float(e0.y);
        ax = fmaf(w0, fmaxf(fmaf(bf_lo(u0), sc.x, sh.x), lo), ax);
        ay = fmaf(w0, fmaxf(fmaf(bf_hi(u0), sc.y, sh.y), lo), ay);
    }
    float di = dinv[w];
    unsigned int us = *(const unsigned int*)&XB[(size_t)w * DH + col];
    float svx = fmaxf(fmaf(bf_lo(us), sc.x, sh.x), lo);
    float svy = fmaxf(fmaf(bf_hi(us), sc.y, sh.y), lo);
    float2 out;
    out.x = fmaf(di, ax, di * di * svx);
    out.y = fmaf(di, ay, di * di * svy);
    *(float2*)&S[(size_t)w * DH + col] = out;
}

// Register-tiled GEMM: X tile (64x128 f32 = 32KB) in LDS, W from global
// (L1/L2-resident broadcast). f32 accumulate + f32 BN stats; bf16 output.
__global__ __launch_bounds__(256) void k_gemm_stats(const float* __restrict__ X,
                                                    const float* __restrict__ W,
                                                    unsigned short* __restrict__ YB,
                                                    float* __restrict__ stats) {
    __shared__ float4 xl4[64 * 32];  // 32 KB: [row][kgroup]
    int t = threadIdx.x;
    int row0 = blockIdx.x * 64;
    // coalesced stage; rows >= NN read garbage from adjacent ws (never used)
    const float4* Xv = (const float4*)(X + (size_t)row0 * DH);
#pragma unroll
    for (int i = 0; i < 8; ++i) xl4[t + i * 256] = Xv[t + i * 256];
    __syncthreads();
    int cg = t & 31, rg = t >> 5;
    const float4* W4 = (const float4*)W;
    float a[8][4] = {};
    for (int k = 0; k < DH; k += 4) {
        float4 w0 = W4[((k + 0) << 5) + cg];
        float4 w1 = W4[((k + 1) << 5) + cg];
        float4 w2 = W4[((k + 2) << 5) + cg];
        float4 w3 = W4[((k + 3) << 5) + cg];
#pragma unroll
        for (int i = 0; i < 8; ++i) {
            float4 xv = xl4[((rg * 8 + i) << 5) + (k >> 2)];  // wave-broadcast
            a[i][0] = fmaf(xv.x, w0.x, a[i][0]);
            a[i][0] = fmaf(xv.y, w1.x, a[i][0]);
            a[i][0] = fmaf(xv.z, w2.x, a[i][0]);
            a[i][0] = fmaf(xv.w, w3.x, a[i][0]);
            a[i][1] = fmaf(xv.x, w0.y, a[i][1]);
            a[i][1] = fmaf(xv.y, w1.y, a[i][1]);
            a[i][1] = fmaf(xv.z, w2.y, a[i][1]);
            a[i][1] = fmaf(xv.w, w3.y, a[i][1]);
            a[i][2] = fmaf(xv.x, w0.z, a[i][2]);
            a[i][2] = fmaf(xv.y, w1.z, a[i][2]);
            a[i][2] = fmaf(xv.z, w2.z, a[i][2]);
            a[i][2] = fmaf(xv.w, w3.z, a[i][2]);
            a[i][3] = fmaf(xv.x, w0.w, a[i][3]);
            a[i][3] = fmaf(xv.y, w1.w, a[i][3]);
            a[i][3] = fmaf(xv.z, w2.w, a[i][3]);
            a[i][3] = fmaf(xv.w, w3.w, a[i][3]);
        }
    }
    int rbase = row0 + rg * 8;
    float ps[4] = {}, q[4] = {};
    int c = cg << 2;
#pragma unroll
    for (int i = 0; i < 8; ++i) {
        int r = rbase + i;
        if (r < NN) {
            ushort4 o4;
            o4.x = bf16rn(a[i][0]); o4.y = bf16rn(a[i][1]);
            o4.z = bf16rn(a[i][2]); o4.w = bf16rn(a[i][3]);
            *(ushort4*)&YB[(size_t)r * DH + c] = o4;
            ps[0] += a[i][0]; ps[1] += a[i][1]; ps[2] += a[i][2]; ps[3] += a[i][3];
            q[0] = fmaf(a[i][0], a[i][0], q[0]); q[1] = fmaf(a[i][1], a[i][1], q[1]);
            q[2] = fmaf(a[i][2], a[i][2], q[2]); q[3] = fmaf(a[i][3], a[i][3], q[3]);
        }
    }
    __syncthreads();  // done reading xl4; reuse as reduction scratch
    float* red = (float*)xl4;
    int base = t * 8;
    red[base + 0] = ps[0]; red[base + 1] = ps[1]; red[base + 2] = ps[2]; red[base + 3] = ps[3];
    red[base + 4] = q[0];  red[base + 5] = q[1];  red[base + 6] = q[2];  red[base + 7] = q[3];
    __syncthreads();
    if (t < 32) {
        float s[8] = {};
        for (int g2 = 0; g2 < 8; ++g2) {
            int b2 = (g2 * 32 + t) * 8;
#pragma unroll
            for (int j = 0; j < 8; ++j) s[j] += red[b2 + j];
        }
        int cc = t << 2;
        atomAddF(&stats[cc + 0], s[0]); atomAddF(&stats[cc + 1], s[1]);
        atomAddF(&stats[cc + 2], s[2]); atomAddF(&stats[cc + 3], s[3]);
        atomAddF(&stats[DH + cc + 0], s[4]); atomAddF(&stats[DH + cc + 1], s[5]);
        atomAddF(&stats[DH + cc + 2], s[6]); atomAddF(&stats[DH + cc + 3], s[7]);
    }
}

// stats -> per-channel scale/shift for fused BN
__global__ void k_bnprep(const float* __restrict__ stats, const float* __restrict__ gamma,
                         const float* __restrict__ beta, float* __restrict__ SC) {
    int j = threadIdx.x;
    if (j >= DH) return;
    const float inv_n = 1.0f / NN;
    float mean = stats[j] * inv_n;
    float var  = stats[DH + j] * inv_n - mean * mean;
    float s    = gamma[j] * rsqrtf(var + BN_EPS);
    SC[j] = s;
    SC[DH + j] = beta[j] - mean * s;
}

// Parallel pool over bf16 features: 782 blocks x 128 rows; BN+ReLU inline;
// atomic flush at graph boundaries only.
__global__ __launch_bounds__(128) void k_pool_partial(const unsigned short* __restrict__ HB,
        const int* __restrict__ batch, const float* __restrict__ SC,
        float* __restrict__ psum) {
    __shared__ int bsh[128];
    int t = threadIdx.x;
    int row0 = blockIdx.x * 128;
    int rl = row0 + t;
    bsh[t] = batch[rl < NN ? rl : (NN - 1)];
    __syncthreads();
    int ro = t >> 5;          // row phase 0..3
    int c  = (t & 31) << 2;   // col group
    float4 sc = *(const float4*)&SC[c];
    float4 sh = *(const float4*)&SC[DH + c];
    int nrows = NN - row0; if (nrows > 128) nrows = 128;
    float4 acc = make_float4(0.f, 0.f, 0.f, 0.f);
    int cur = -1;
    for (int rr = ro; rr < nrows; rr += 4) {
        int g = bsh[rr];
        if (g != cur) {
            if (cur >= 0) {
                float* p = &psum[(cur << 7) + c];
                atomAddF(p + 0, acc.x); atomAddF(p + 1, acc.y);
                atomAddF(p + 2, acc.z); atomAddF(p + 3, acc.w);
            }
            acc = make_float4(0.f, 0.f, 0.f, 0.f);
            cur = g;
        }
        uint2 u = *(const uint2*)&HB[(size_t)(row0 + rr) * DH + c];
        acc.x += fmaxf(fmaf(bf_lo(u.x), sc.x, sh.x), 0.0f);
        acc.y += fmaxf(fmaf(bf_hi(u.x), sc.y, sh.y), 0.0f);
        acc.z += fmaxf(fmaf(bf_lo(u.y), sc.z, sh.z), 0.0f);
        acc.w += fmaxf(fmaf(bf_hi(u.y), sc.w, sh.w), 0.0f);
    }
    if (cur >= 0) {
        float* p = &psum[(cur << 7) + c];
        atomAddF(p + 0, acc.x); atomAddF(p + 1, acc.y);
        atomAddF(p + 2, acc.z); atomAddF(p + 3, acc.w);
    }
}

// One block per graph: divide by count, hidden GEMV, reduce to scalar output.
__global__ __launch_bounds__(128) void k_mlp(const float* __restrict__ psum,
        const int* __restrict__ starts, const float* __restrict__ w1,
        const float* __restrict__ b1, const float* __restrict__ w2,
        const float* __restrict__ b2, float* __restrict__ out) {
    __shared__ float pl[DH];
    __shared__ float red[DH];
    int g = blockIdx.x, j = threadIdx.x;  // 128 threads
    float cnt = fmaxf((float)(starts[g + 1] - starts[g]), 1.0f);
    pl[j] = psum[(g << 7) + j] / cnt;
    __syncthreads();
    float s = b1[j];
#pragma unroll 8
    for (int k = 0; k < DH; ++k)
        s = fmaf(pl[k], w1[(k << 7) + j], s);
    red[j] = fmaxf(s, 0.0f) * w2[j];
    __syncthreads();
    for (int st = 64; st > 0; st >>= 1) {
        if (j < st) red[j] += red[j + st];
        __syncthreads();
    }
    if (j == 0) out[g] = red[0] + b2[0];
}

extern "C" void kernel_launch(void* const* d_in, const int* in_sizes, int n_in,
                              void* d_out, int out_size, void* d_ws, size_t ws_size,
                              hipStream_t stream) {
    const float* x      = (const float*)d_in[0];
    const int*   ei     = (const int*)d_in[1];
    const int*   batch  = (const int*)d_in[2];
    const float* conv_w = (const float*)d_in[3];
    // d_in[4] = conv_b: cancels inside BatchNorm -> unused
    const float* bn_g   = (const float*)d_in[5];
    const float* bn_b   = (const float*)d_in[6];
    const float* w1     = (const float*)d_in[7];
    const float* b1     = (const float*)d_in[8];
    const float* w2     = (const float*)d_in[9];
    const float* b2     = (const float*)d_in[10];
    const int* src = ei;
    const int* dst = ei + NE;

    float*          bufS     = (float*)d_ws;                 // NN*DH f32 (aggregate out)
    unsigned short* xbf      = (unsigned short*)(bufS + (size_t)NN * DH);  // NN*DH bf16
    float*          dinv     = (float*)(xbf + (size_t)NN * DH);            // NN
    float*          stats    = dinv + NN;                    // 256
    float*          psum     = stats + 256;                  // NG*DH
    int*            starts   = (int*)(psum + NG * DH);       // 72
    int*            cnt      = starts + 72;                  // NN
    int*            off      = cnt + NN;                     // NN
    int*            cursor   = off + NN;                     // NN
    int*            gcounter = cursor + NN;                  // 8
    float*          idsc     = (float*)(gcounter + 8);       // 256
    float*          bnsc     = idsc + 256;                   // 256
    int2*           edata    = (int2*)(bnsc + 256);          // NE int2

    // one-time CSR build + input bf16 conversion
    k_zero   <<<(NN + 255) / 256, 256, 0, stream>>>(cnt, gcounter, idsc, psum);
    k_convert<<<(NN * DH / 4 + 255) / 256, 256, 0, stream>>>(x, (ushort4*)xbf);
    k_count  <<<(NE + 255) / 256, 256, 0, stream>>>(dst, cnt);
    k_offsets<<<(NN + 255) / 256, 256, 0, stream>>>(cnt, off, cursor, dinv, gcounter);
    k_permute<<<(NE + 255) / 256, 256, 0, stream>>>(src, dst, dinv, cursor, edata);
    k_starts <<<(NN + 255) / 256, 256, 0, stream>>>(batch, starts);

    const float* SC = idsc;
    float lo = NEG_INF;  // layer 0: no BN, no ReLU on raw input
    for (int l = 0; l < NL; ++l) {
        k_aggregate <<<25000, 256, 0, stream>>>(xbf, edata, off, cnt, dinv, SC, lo, bufS, stats);
        k_gemm_stats<<<(NN + 63) / 64, 256, 0, stream>>>(
            bufS, conv_w + (size_t)l * DH * DH, xbf, stats);
        k_bnprep    <<<1, 128, 0, stream>>>(stats, bn_g + l * DH, bn_b + l * DH, bnsc);
        SC = bnsc; lo = 0.0f;
    }
    k_pool_partial<<<(NN + 127) / 128, 128, 0, stream>>>(xbf, batch, bnsc, psum);
    k_mlp<<<NG, 128, 0, stream>>>(psum, starts, w1, b1, w2, b2, (float*)d_out);
}